// Round 23
// baseline (183.824 us; speedup 1.0000x reference)
//
#include <hip/hip_runtime.h>
#include <math.h>

#define IDIM 2048
#define NE   64
#define TOPK 8
#define NB   16384
#define BM   32            // rows per block
#define BK   64            // k per chunk
#define NCH  (IDIM / BK)   // 32 chunks (monolithic path)
#define NQ   4             // K quarters (split path)
#define KQ   512           // K per quarter
#define NCHQ 8             // tiles per quarter
#define TAU  1e-4f

// ws float layout: [0..63] f counts, [64..127] p sums, [128] z sum,
//                  [129] (int) flag count, [130..130+NB) (int) flagged row list
// byte WSPLIT_BYTE..: pre-split W tiles (32 tiles x (16KB hi + 16KB lo))
// byte PART_BYTE..: fp32 partial logits [NQ][NB][128] (split path)
#define WS_CNT 129
#define WS_LIST 130
#define WSPLIT_BYTE 66560
#define WSPLIT_REQ  (WSPLIT_BYTE + NCH * 32768)
#define PART_BYTE   (WSPLIT_BYTE + NCH * 32768)
#define SPLIT_REQ   (PART_BYTE + (size_t)NQ * NB * 128 * 4)

typedef __attribute__((ext_vector_type(8))) short bf16x8_t;  // 8 bf16 = 4 VGPRs
typedef __attribute__((ext_vector_type(4))) float f32x4_t;   // MFMA acc

__device__ __forceinline__ float softplusf(float v) {
    return (v > 0.f) ? (v + log1pf(expf(-v))) : log1pf(expf(v));
}
__device__ __forceinline__ double softplus_d(double v) {
    return (v > 0.0) ? (v + log1p(exp(-v))) : log1p(exp(v));
}

// deterministic RNE fp32 -> bf16 bits
__device__ __forceinline__ short f2bf(float f) {
    unsigned u = __float_as_uint(f);
    unsigned r = (u + 0x7FFFu + ((u >> 16) & 1u)) >> 16;
    return (short)r;
}
__device__ __forceinline__ float bf2f(short s) {
    return __uint_as_float(((unsigned)(unsigned short)s) << 16);
}

__global__ void init_ws_kernel(float* ws) {
    int t = threadIdx.x;
    if (t < WS_LIST) ws[t] = 0.0f;
}

__device__ __forceinline__ void split8(const float4 v0, const float4 v1,
                                       bf16x8_t& H, bf16x8_t& L) {
    float fv[8] = {v0.x, v0.y, v0.z, v0.w, v1.x, v1.y, v1.z, v1.w};
    #pragma unroll
    for (int q = 0; q < 8; ++q) {
        short hb = f2bf(fv[q]);
        short lb = f2bf(fv[q] - bf2f(hb));
        H[q] = hb; L[q] = lb;
    }
}

__device__ __forceinline__ void cvt_slot(const float4 v0, const float4 v1,
                                         char* hiP, char* loP, int off) {
    bf16x8_t H, L;
    split8(v0, v1, H, L);
    *(bf16x8_t*)(hiP + off) = H;
    *(bf16x8_t*)(loP + off) = L;
}

// ---------------- pass 0: init ws + pre-split W into swizzled LDS tile images ----------------
__global__ __launch_bounds__(256) void prep_kernel(
    const float* __restrict__ Wg, const float* __restrict__ Wn,
    char* __restrict__ wsW, float* __restrict__ ws)
{
    if (blockIdx.x == 128) {             // merged init
        if (threadIdx.x < WS_LIST) ws[threadIdx.x] = 0.0f;
        return;
    }
    int g = blockIdx.x * 256 + threadIdx.x;   // 0..32767
    int t = g >> 10, i = g & 1023;
    int row = i >> 3, wslot = i & 7;
    int kslot = wslot ^ (row & 7);
    const float* src = (row < 64 ? Wg + (size_t)row * IDIM
                                 : Wn + (size_t)(row - 64) * IDIM) + t * BK + kslot * 8;
    float4 v0 = *(const float4*)src;
    float4 v1 = *(const float4*)(src + 4);
    bf16x8_t H, L;
    split8(v0, v1, H, L);
    char* dst = wsW + (size_t)t * 32768;
    *(bf16x8_t*)(dst + i * 16)         = H;
    *(bf16x8_t*)(dst + 16384 + i * 16) = L;
}

// ---------------- pass 1a (split): quarter-K GEMM -> fp32 partials ----------------
// LDS exactly 40960B -> 4 blocks/CU: AH@0 AL@4096 BH@8192 BL@24576
__global__ __launch_bounds__(512, 4) void gemm_quarter_kernel(
    const float* __restrict__ x, const char* __restrict__ wsW,
    float* __restrict__ part)
{
    __shared__ char smem[40960] __attribute__((aligned(16)));
    char* AH = smem;
    char* AL = smem + 4096;
    char* BH = smem + 8192;
    char* BL = smem + 24576;

    const int u   = threadIdx.x;
    const int w   = u >> 6;
    const int l   = u & 63;
    const int lr  = l & 15;
    const int lg4 = l >> 4;
    const int s7  = lr & 7;
    const int q   = blockIdx.x & 3;
    const int row0 = (blockIdx.x >> 2) * BM;
    float* pb = part + (size_t)q * NB * 128;

    const int ar  = (u >> 3) & 31;
    const int ac  = u & 7;
    const int aoff = ar * 128 + (((ac ^ (ar & 7)) & 7) << 4);
    const float* pa = x + (size_t)(row0 + ar) * IDIM + q * KQ + ac * 8;

    f32x4_t acc[2];
    #pragma unroll
    for (int mt = 0; mt < 2; ++mt) {
        f32x4_t z = {0.f, 0.f, 0.f, 0.f};
        acc[mt] = z;
    }

    float4 ra0, ra1;
    int4 w0, w1, w2, w3;

#define QLOADT(tt) { const int k0 = (tt) * BK;                                  \
    if (u < 256) { ra0 = *(const float4*)(pa + k0);                             \
                   ra1 = *(const float4*)(pa + k0 + 4); }                       \
    const char* s_ = wsW + (size_t)(q * NCHQ + (tt)) * 32768 + u * 16;          \
    w0 = *(const int4*)(s_);          w1 = *(const int4*)(s_ + 8192);           \
    w2 = *(const int4*)(s_ + 16384);  w3 = *(const int4*)(s_ + 24576); }

    QLOADT(0);

    for (int t = 0; t < NCHQ; ++t) {
        __syncthreads();
        if (u < 256) cvt_slot(ra0, ra1, AH, AL, aoff);
        *(int4*)(BH + u * 16)        = w0;
        *(int4*)(BH + 8192 + u * 16) = w1;
        *(int4*)(BL + u * 16)        = w2;
        *(int4*)(BL + 8192 + u * 16) = w3;
        if (t + 1 < NCHQ) QLOADT(t + 1);
        __syncthreads();

        #pragma unroll
        for (int ks = 0; ks < 2; ++ks) {
            const int so = (((ks * 4 + lg4) ^ s7) << 4);
            bf16x8_t ah[2], al_[2], bh, bl;
            #pragma unroll
            for (int mt = 0; mt < 2; ++mt) {
                const int o = (mt * 16 + lr) * 128 + so;
                ah[mt]  = *(const bf16x8_t*)(AH + o);
                al_[mt] = *(const bf16x8_t*)(AL + o);
            }
            {
                const int o = (w * 16 + lr) * 128 + so;
                bh = *(const bf16x8_t*)(BH + o);
                bl = *(const bf16x8_t*)(BL + o);
            }
            #pragma unroll
            for (int mt = 0; mt < 2; ++mt) {
                acc[mt] = __builtin_amdgcn_mfma_f32_16x16x32_bf16(ah[mt],  bh, acc[mt], 0, 0, 0);
                acc[mt] = __builtin_amdgcn_mfma_f32_16x16x32_bf16(ah[mt],  bl, acc[mt], 0, 0, 0);
                acc[mt] = __builtin_amdgcn_mfma_f32_16x16x32_bf16(al_[mt], bh, acc[mt], 0, 0, 0);
            }
        }
    }

    // ---- store partials (C/D: col=lane&15, row=(lane>>4)*4+reg) ----
    #pragma unroll
    for (int mt = 0; mt < 2; ++mt)
        #pragma unroll
        for (int r = 0; r < 4; ++r)
            pb[(size_t)(row0 + mt * 16 + lg4 * 4 + r) * 128 + (w * 16 + lr)] = acc[mt][r];
}

// ---------------- pass 1b (split): gating from partials + INLINE fp64 recheck ----------------
// 512 blocks x 32 rows; 8 waves x 4 rows. Flagged rows rechecked in-block
// (coalesced lane<->k, fp64 butterfly) -> global list stays empty.
__global__ __launch_bounds__(512) void gating_kernel(
    const float* __restrict__ part,
    const float* __restrict__ x,
    const float* __restrict__ Wg, const float* __restrict__ Wn,
    const float* __restrict__ noise, const float* __restrict__ bg,
    float* __restrict__ out_w, float* __restrict__ out_i,
    float* __restrict__ ws)
{
    __shared__ float sP[NE];
    __shared__ float sF[NE];
    __shared__ float sZ[1];
    __shared__ int   sFn;
    __shared__ int   sFlag[32];
    __shared__ double sRedD[128];
    const int u = threadIdx.x;
    const int w = u >> 6, l = u & 63;
    const int row0 = blockIdx.x * 32;
    const float* p0 = part;
    const float* p1 = part + (size_t)NB * 128;
    const float* p2 = part + 2 * (size_t)NB * 128;
    const float* p3 = part + 3 * (size_t)NB * 128;

    if (u < NE) { sP[u] = 0.f; sF[u] = 0.f; }
    if (u == 0) { sZ[0] = 0.f; sFn = 0; }
    __syncthreads();

    float pacc = 0.f, zacc = 0.f;
    #pragma unroll 1
    for (int rr = 0; rr < 4; ++rr) {
        const int grow = row0 + w * 4 + rr;
        const size_t b = (size_t)grow * 128;
        float lg   = ((p0[b + l] + p1[b + l]) + (p2[b + l] + p3[b + l])) + bg[l];
        float npre = (p0[b + 64 + l] + p1[b + 64 + l]) + (p2[b + 64 + l] + p3[b + 64 + l]);
        float vcur = fmaf(noise[(size_t)grow * NE + l], softplusf(npre), lg);

        float tkv[9]; int tki[9];
        #pragma unroll
        for (int k = 0; k < 9; ++k) {
            float mv = vcur; int mi = l;
            #pragma unroll
            for (int o = 32; o > 0; o >>= 1) {
                float ov = __shfl_xor(mv, o);
                int   oi = __shfl_xor(mi, o);
                if (ov > mv || (ov == mv && oi < mi)) { mv = ov; mi = oi; }
            }
            tkv[k] = mv; tki[k] = mi;
            if (l == mi) vcur = -1e30f;
        }

        float m0 = tkv[0], s = 0.f, wk[TOPK];
        #pragma unroll
        for (int k = 0; k < TOPK; ++k) { wk[k] = expf(tkv[k] - m0); s += wk[k]; }
        float inv = 1.f / s;
        float myw = 0.f; int myi = 0;
        #pragma unroll
        for (int k = 0; k < TOPK; ++k)
            if (l == k) { myw = wk[k] * inv; myi = tki[k]; }
        if (l < TOPK) {
            out_w[(size_t)grow * TOPK + l] = myw;
            out_i[(size_t)grow * TOPK + l] = (float)myi;
        }

        if (l == 0) {
            atomicAdd(&sF[tki[0]], 1.f);
            float ming = 1e30f;
            #pragma unroll
            for (int k = 0; k < 8; ++k) ming = fminf(ming, tkv[k] - tkv[k + 1]);
            if (ming < TAU) {
                int slot = atomicAdd(&sFn, 1);
                sFlag[slot] = grow;      // slot < 32 by construction
            }
        }

        float rm = lg;
        #pragma unroll
        for (int o = 32; o > 0; o >>= 1) rm = fmaxf(rm, __shfl_xor(rm, o));
        float pe = expf(lg - rm);
        float ssum = pe;
        #pragma unroll
        for (int o = 32; o > 0; o >>= 1) ssum += __shfl_xor(ssum, o);
        pacc += pe / ssum;
        if (l == 0) { float lse = rm + logf(ssum); zacc += lse * lse; }
    }

    atomicAdd(&sP[l], pacc);
    if (l == 0) atomicAdd(sZ, zacc);
    __syncthreads();
    if (u < NE) {
        atomicAdd(&ws[u],      sF[u]);
        atomicAdd(&ws[NE + u], sP[u]);
    }
    if (u == 0) atomicAdd(&ws[2 * NE], sZ[0]);
    __syncthreads();

    // ---- inline fp64 recheck of flagged rows (usually 0 or 1 per block) ----
    const int fn = sFn;
    #pragma unroll 1
    for (int fi = 0; fi < fn; ++fi) {
        const int row = sFlag[fi];
        const float* xr = x + (size_t)row * IDIM;

        // hoist x row: lane covers k = i*256 + l*4 (coalesced)
        float4 xv[8];
        #pragma unroll
        for (int i = 0; i < 8; ++i)
            xv[i] = *(const float4*)(xr + i * 256 + l * 4);

        #pragma unroll 1
        for (int si = 0; si < 16; ++si) {
            const int s = w * 16 + si;
            const float* wr = (s < 64) ? (Wg + (size_t)s * IDIM)
                                       : (Wn + (size_t)(s - 64) * IDIM);
            double a = 0.0;
            #pragma unroll
            for (int i = 0; i < 8; ++i) {
                float4 wvv = *(const float4*)(wr + i * 256 + l * 4);
                a = fma((double)xv[i].x, (double)wvv.x, a);
                a = fma((double)xv[i].y, (double)wvv.y, a);
                a = fma((double)xv[i].z, (double)wvv.z, a);
                a = fma((double)xv[i].w, (double)wvv.w, a);
            }
            #pragma unroll
            for (int o = 32; o > 0; o >>= 1)
                a += __shfl_xor(a, o);
            if (l == 0) sRedD[s] = a;
        }
        __syncthreads();

        if (u < 64) {
            const int l64 = u;
            double g = sRedD[l64];
            double n = sRedD[64 + l64];
            double lgd = g + (double)bg[l64];
            double nz = (double)noise[(size_t)row * NE + l64];
            double vcur = fma(nz, softplus_d(n), lgd);

            double tkv[TOPK]; int tki[TOPK];
            #pragma unroll
            for (int k = 0; k < TOPK; ++k) {
                double mv = vcur; int mi = l64;
                #pragma unroll
                for (int o = 32; o > 0; o >>= 1) {
                    double ov = __shfl_xor(mv, o);
                    int    oi = __shfl_xor(mi, o);
                    if (ov > mv || (ov == mv && oi < mi)) { mv = ov; mi = oi; }
                }
                tkv[k] = mv; tki[k] = mi;
                if (l64 == mi) vcur = -1e300;
            }
            double m0 = tkv[0], s = 0.0, wk[TOPK];
            #pragma unroll
            for (int k = 0; k < TOPK; ++k) { wk[k] = exp(tkv[k] - m0); s += wk[k]; }
            double inv = 1.0 / s;
            float myw = 0.f; int myi = 0;
            #pragma unroll
            for (int k = 0; k < TOPK; ++k)
                if (l64 == k) { myw = (float)(wk[k] * inv); myi = tki[k]; }
            if (l64 < TOPK) {
                out_w[(size_t)row * TOPK + l64] = myw;
                out_i[(size_t)row * TOPK + l64] = (float)myi;
            }
        }
        __syncthreads();   // sRedD reuse safe
    }
}

// ---------------- pass 1 (fallback): R16 monolithic GEMM + gating ----------------
template<bool PRE>
__global__ __launch_bounds__(512, 4) void gate_main_kernel(
    const float* __restrict__ x, const float* __restrict__ noise,
    const float* __restrict__ Wg, const float* __restrict__ bg,
    const float* __restrict__ Wn, const char* __restrict__ wsW,
    float* __restrict__ out_w, float* __restrict__ out_i,
    float* __restrict__ ws, int listCap)
{
    __shared__ char smem[41488] __attribute__((aligned(16)));
    char* AH = smem;
    char* AL = smem + 4096;
    char* BH = smem + 8192;
    char* BL = smem + 24576;
    float* sP = (float*)(smem + 40960);
    float* sF = (float*)(smem + 41216);
    float* sZ = (float*)(smem + 41472);
    float* sL = (float*)smem;

    const int u   = threadIdx.x;
    const int w   = u >> 6;
    const int l   = u & 63;
    const int lr  = l & 15;
    const int lg4 = l >> 4;
    const int s7  = lr & 7;
    const int row0 = blockIdx.x * BM;

    if (u < NE) { sP[u] = 0.f; sF[u] = 0.f; }
    if (u == 0) sZ[0] = 0.f;

    const int ar  = (u >> 3) & 31;
    const int ac  = u & 7;
    const int aoff = ar * 128 + (((ac ^ (ar & 7)) & 7) << 4);
    const float* pa = x + (size_t)(row0 + ar) * IDIM + ac * 8;

    const int br  = u >> 3;
    const float* pg = Wg + (size_t)br * IDIM + ac * 8;
    const float* pn = Wn + (size_t)br * IDIM + ac * 8;
    const int woff = br * 128 + ((ac ^ (br & 7)) << 4);

    f32x4_t acc[2];
    #pragma unroll
    for (int mt = 0; mt < 2; ++mt) {
        f32x4_t z = {0.f, 0.f, 0.f, 0.f};
        acc[mt] = z;
    }

    float4 ra0, ra1;
    int4 w0, w1, w2, w3;
    float4 g0, g1, n0, n1;

#define LOADT(tt) { const int k0 = (tt) * BK;                                   \
    if (u < 256) { ra0 = *(const float4*)(pa + k0);                             \
                   ra1 = *(const float4*)(pa + k0 + 4); }                       \
    if constexpr (PRE) {                                                        \
        const char* s_ = wsW + (size_t)(tt) * 32768 + u * 16;                   \
        w0 = *(const int4*)(s_);          w1 = *(const int4*)(s_ + 8192);       \
        w2 = *(const int4*)(s_ + 16384);  w3 = *(const int4*)(s_ + 24576);      \
    } else {                                                                    \
        g0 = *(const float4*)(pg + k0);   g1 = *(const float4*)(pg + k0 + 4);   \
        n0 = *(const float4*)(pn + k0);   n1 = *(const float4*)(pn + k0 + 4);   \
    } }

    LOADT(0);

    for (int t = 0; t < NCH; ++t) {
        __syncthreads();
        if (u < 256) cvt_slot(ra0, ra1, AH, AL, aoff);
        if constexpr (PRE) {
            *(int4*)(BH + u * 16)        = w0;
            *(int4*)(BH + 8192 + u * 16) = w1;
            *(int4*)(BL + u * 16)        = w2;
            *(int4*)(BL + 8192 + u * 16) = w3;
        } else {
            cvt_slot(g0, g1, BH, BL, woff);
            cvt_slot(n0, n1, BH, BL, woff + 8192);
        }
        if (t + 1 < NCH) LOADT(t + 1);
        __syncthreads();

        #pragma unroll
        for (int ks = 0; ks < 2; ++ks) {
            const int so = (((ks * 4 + lg4) ^ s7) << 4);
            bf16x8_t ah[2], al_[2], bh, bl;
            #pragma unroll
            for (int mt = 0; mt < 2; ++mt) {
                const int o = (mt * 16 + lr) * 128 + so;
                ah[mt]  = *(const bf16x8_t*)(AH + o);
                al_[mt] = *(const bf16x8_t*)(AL + o);
            }
            {
                const int o = (w * 16 + lr) * 128 + so;
                bh = *(const bf16x8_t*)(BH + o);
                bl = *(const bf16x8_t*)(BL + o);
            }
            #pragma unroll
            for (int mt = 0; mt < 2; ++mt) {
                acc[mt] = __builtin_amdgcn_mfma_f32_16x16x32_bf16(ah[mt],  bh, acc[mt], 0, 0, 0);
                acc[mt] = __builtin_amdgcn_mfma_f32_16x16x32_bf16(ah[mt],  bl, acc[mt], 0, 0, 0);
                acc[mt] = __builtin_amdgcn_mfma_f32_16x16x32_bf16(al_[mt], bh, acc[mt], 0, 0, 0);
            }
        }
    }
    __syncthreads();

    #pragma unroll
    for (int mt = 0; mt < 2; ++mt)
        #pragma unroll
        for (int r = 0; r < 4; ++r)
            sL[(mt * 16 + lg4 * 4 + r) * 132 + (w * 16 + lr)] = acc[mt][r];
    __syncthreads();

    float pacc = 0.f, zacc = 0.f;
    #pragma unroll 1
    for (int rr = 0; rr < 4; ++rr) {
        const int r = w * 4 + rr;
        const int grow = row0 + r;
        float lg   = sL[r * 132 + l] + bg[l];
        float npre = sL[r * 132 + 64 + l];
        float vcur = fmaf(noise[(size_t)grow * NE + l], softplusf(npre), lg);

        float tkv[9]; int tki[9];
        #pragma unroll
        for (int k = 0; k < 9; ++k) {
            float mv = vcur; int mi = l;
            #pragma unroll
            for (int o = 32; o > 0; o >>= 1) {
                float ov = __shfl_xor(mv, o);
                int   oi = __shfl_xor(mi, o);
                if (ov > mv || (ov == mv && oi < mi)) { mv = ov; mi = oi; }
            }
            tkv[k] = mv; tki[k] = mi;
            if (l == mi) vcur = -1e30f;
        }

        float m0 = tkv[0], s = 0.f, wk[TOPK];
        #pragma unroll
        for (int k = 0; k < TOPK; ++k) { wk[k] = expf(tkv[k] - m0); s += wk[k]; }
        float inv = 1.f / s;
        float myw = 0.f; int myi = 0;
        #pragma unroll
        for (int k = 0; k < TOPK; ++k)
            if (l == k) { myw = wk[k] * inv; myi = tki[k]; }
        if (l < TOPK) {
            out_w[(size_t)grow * TOPK + l] = myw;
            out_i[(size_t)grow * TOPK + l] = (float)myi;
        }

        if (l == 0) {
            atomicAdd(&sF[tki[0]], 1.f);
            float ming = 1e30f;
            #pragma unroll
            for (int k = 0; k < 8; ++k) ming = fminf(ming, tkv[k] - tkv[k + 1]);
            if (ming < TAU) {
                int slot = atomicAdd((int*)&ws[WS_CNT], 1);
                if (slot < listCap) ((int*)ws)[WS_LIST + slot] = grow;
            }
        }

        float rm = lg;
        #pragma unroll
        for (int o = 32; o > 0; o >>= 1) rm = fmaxf(rm, __shfl_xor(rm, o));
        float pe = expf(lg - rm);
        float ssum = pe;
        #pragma unroll
        for (int o = 32; o > 0; o >>= 1) ssum += __shfl_xor(ssum, o);
        pacc += pe / ssum;
        if (l == 0) { float lse = rm + logf(ssum); zacc += lse * lse; }
    }

    atomicAdd(&sP[l], pacc);
    if (l == 0) atomicAdd(sZ, zacc);
    __syncthreads();
    if (u < NE) {
        atomicAdd(&ws[u],      sF[u]);
        atomicAdd(&ws[NE + u], sP[u]);
    }
    if (u == 0) atomicAdd(&ws[2 * NE], sZ[0]);
}

// ---------------- pass 2: finalize scalars (block 0) + fp64 recheck, COALESCED ----------------
// Split path: cnt==0 -> finalize only (~3 us). Fallback paths: full recheck.
__global__ __launch_bounds__(1024) void recheck_finalize_kernel(
    const float* __restrict__ x, const float* __restrict__ noise,
    const float* __restrict__ Wg, const float* __restrict__ bg,
    const float* __restrict__ Wn,
    float* __restrict__ out_w, float* __restrict__ out_i, float* __restrict__ out_s,
    const float* __restrict__ ws, int listCap)
{
    __shared__ double sRed[128];
    const int t = threadIdx.x;

    if (blockIdx.x == 0 && t < 64) {     // finalize scalars (wave 0, no barriers)
        float v = (ws[t] / (float)NB) * (ws[NE + t] / (float)NB);
        #pragma unroll
        for (int o = 32; o > 0; o >>= 1) v += __shfl_down(v, o);
        if (t == 0) {
            out_s[0] = (float)NE * v;
            out_s[1] = ws[2 * NE] / (float)NB;
        }
    }

    const int* wsi = (const int*)ws;
    int cnt = wsi[WS_CNT];
    if (cnt > listCap) cnt = listCap;
    if (cnt <= 0) return;

    const int wv   = t >> 6;             // wave 0..15, owns slots [wv*8, wv*8+8)
    const int lane = t & 63;

    for (int bi = blockIdx.x; bi < cnt; bi += gridDim.x) {
        const int row = wsi[WS_LIST + bi];
        const float* xr = x + (size_t)row * IDIM;

        float4 xv[8];
        #pragma unroll
        for (int i = 0; i < 8; ++i)
            xv[i] = *(const float4*)(xr + i * 256 + lane * 4);

        #pragma unroll 1
        for (int si = 0; si < 8; ++si) {
            const int s = wv * 8 + si;
            const float* wr = (s < 64) ? (Wg + (size_t)s * IDIM)
                                       : (Wn + (size_t)(s - 64) * IDIM);
            double a = 0.0;
            #pragma unroll
            for (int i = 0; i < 8; ++i) {
                float4 wvv = *(const float4*)(wr + i * 256 + lane * 4);
                a = fma((double)xv[i].x, (double)wvv.x, a);
                a = fma((double)xv[i].y, (double)wvv.y, a);
                a = fma((double)xv[i].z, (double)wvv.z, a);
                a = fma((double)xv[i].w, (double)wvv.w, a);
            }
            #pragma unroll
            for (int o = 32; o > 0; o >>= 1)
                a += __shfl_xor(a, o);
            if (lane == 0) sRed[s] = a;
        }
        __syncthreads();

        if (t < 64) {
            const int l64 = t;
            double g = sRed[l64];
            double n = sRed[64 + l64];
            double lgd = g + (double)bg[l64];
            double nz = (double)noise[(size_t)row * NE + l64];
            double vcur = fma(nz, softplus_d(n), lgd);

            double tkv[TOPK]; int tki[TOPK];
            #pragma unroll
            for (int k = 0; k < TOPK; ++k) {
                double mv = vcur; int mi = l64;
                #pragma unroll
                for (int o = 32; o > 0; o >>= 1) {
                    double ov = __shfl_xor(mv, o);
                    int    oi = __shfl_xor(mi, o);
                    if (ov > mv || (ov == mv && oi < mi)) { mv = ov; mi = oi; }
                }
                tkv[k] = mv; tki[k] = mi;
                if (l64 == mi) vcur = -1e300;
            }
            double m0 = tkv[0], s = 0.0, wk[TOPK];
            #pragma unroll
            for (int k = 0; k < TOPK; ++k) { wk[k] = exp(tkv[k] - m0); s += wk[k]; }
            double inv = 1.0 / s;
            float myw = 0.f; int myi = 0;
            #pragma unroll
            for (int k = 0; k < TOPK; ++k)
                if (l64 == k) { myw = (float)(wk[k] * inv); myi = tki[k]; }
            if (l64 < TOPK) {
                out_w[(size_t)row * TOPK + l64] = myw;
                out_i[(size_t)row * TOPK + l64] = (float)myi;
            }
        }
        __syncthreads();
    }
}

extern "C" void kernel_launch(void* const* d_in, const int* in_sizes, int n_in,
                              void* d_out, int out_size, void* d_ws, size_t ws_size,
                              hipStream_t stream) {
    const float* x     = (const float*)d_in[0];
    const float* noise = (const float*)d_in[1];
    const float* Wg    = (const float*)d_in[2];
    const float* bg    = (const float*)d_in[3];
    const float* Wn    = (const float*)d_in[4];
    float* out = (float*)d_out;
    float* ws  = (float*)d_ws;
    char*  wsW = (char*)d_ws + WSPLIT_BYTE;

    long cap = (long)(ws_size / 4) - WS_LIST;
    int listCap = (int)(cap < 0 ? 0 : (cap > NB ? NB : cap));
    const bool pre   = ws_size >= (size_t)WSPLIT_REQ;
    const bool split = ws_size >= (size_t)SPLIT_REQ;

    if (split) {
        float* part = (float*)((char*)d_ws + PART_BYTE);
        hipLaunchKernelGGL(prep_kernel, dim3(129), dim3(256), 0, stream, Wg, Wn, wsW, ws);
        hipLaunchKernelGGL(gemm_quarter_kernel, dim3(NQ * NB / BM), dim3(512), 0, stream,
                           x, wsW, part);
        hipLaunchKernelGGL(gating_kernel, dim3(NB / 32), dim3(512), 0, stream,
                           part, x, Wg, Wn, noise, bg,
                           out, out + (size_t)NB * TOPK, ws);
    } else if (pre) {
        hipLaunchKernelGGL(prep_kernel, dim3(129), dim3(256), 0, stream, Wg, Wn, wsW, ws);
        hipLaunchKernelGGL(gate_main_kernel<true>, dim3(NB / BM), dim3(512), 0, stream,
                           x, noise, Wg, bg, Wn, wsW,
                           out, out + (size_t)NB * TOPK, ws, listCap);
    } else {
        hipLaunchKernelGGL(init_ws_kernel, dim3(1), dim3(256), 0, stream, ws);
        hipLaunchKernelGGL(gate_main_kernel<false>, dim3(NB / BM), dim3(512), 0, stream,
                           x, noise, Wg, bg, Wn, wsW,
                           out, out + (size_t)NB * TOPK, ws, listCap);
    }
    hipLaunchKernelGGL(recheck_finalize_kernel, dim3(512), dim3(1024), 0, stream,
                       x, noise, Wg, bg, Wn,
                       out, out + (size_t)NB * TOPK, out + 2 * (size_t)NB * TOPK,
                       ws, listCap);
}

// Round 24
// 117.863 us; speedup vs baseline: 1.5596x; 1.5596x over previous
//
#include <hip/hip_runtime.h>
#include <math.h>

#define IDIM 2048
#define NE   64
#define TOPK 8
#define NB   16384
#define BM   32            // rows per block
#define BK   64            // k per chunk
#define NCH  (IDIM / BK)   // 32 chunks (monolithic path)
#define NQ   4             // K quarters (split path)
#define KQ   512           // K per quarter
#define NCHQ 8             // tiles per quarter
#define TAU  1e-4f

// ws float layout: [0..63] f counts, [64..127] p sums, [128] z sum,
//                  [129] (int) flag count, [130..130+NB) (int) flagged row list
// byte WSPLIT_BYTE..: pre-split W tiles (32 tiles x (16KB hi + 16KB lo))
// byte PART_BYTE..: fp32 partial logits [NQ][NB][128] (split path)
#define WS_CNT 129
#define WS_LIST 130
#define WSPLIT_BYTE 66560
#define WSPLIT_REQ  (WSPLIT_BYTE + NCH * 32768)
#define PART_BYTE   (WSPLIT_BYTE + NCH * 32768)
#define SPLIT_REQ   (PART_BYTE + (size_t)NQ * NB * 128 * 4)

typedef __attribute__((ext_vector_type(8))) short bf16x8_t;  // 8 bf16 = 4 VGPRs
typedef __attribute__((ext_vector_type(4))) float f32x4_t;   // MFMA acc

__device__ __forceinline__ float softplusf(float v) {
    return (v > 0.f) ? (v + log1pf(expf(-v))) : log1pf(expf(v));
}
__device__ __forceinline__ double softplus_d(double v) {
    return (v > 0.0) ? (v + log1p(exp(-v))) : log1p(exp(v));
}

// deterministic RNE fp32 -> bf16 bits
__device__ __forceinline__ short f2bf(float f) {
    unsigned u = __float_as_uint(f);
    unsigned r = (u + 0x7FFFu + ((u >> 16) & 1u)) >> 16;
    return (short)r;
}
__device__ __forceinline__ float bf2f(short s) {
    return __uint_as_float(((unsigned)(unsigned short)s) << 16);
}

__global__ void init_ws_kernel(float* ws) {
    int t = threadIdx.x;
    if (t < WS_LIST) ws[t] = 0.0f;
}

__device__ __forceinline__ void split8(const float4 v0, const float4 v1,
                                       bf16x8_t& H, bf16x8_t& L) {
    float fv[8] = {v0.x, v0.y, v0.z, v0.w, v1.x, v1.y, v1.z, v1.w};
    #pragma unroll
    for (int q = 0; q < 8; ++q) {
        short hb = f2bf(fv[q]);
        short lb = f2bf(fv[q] - bf2f(hb));
        H[q] = hb; L[q] = lb;
    }
}

__device__ __forceinline__ void cvt_slot(const float4 v0, const float4 v1,
                                         char* hiP, char* loP, int off) {
    bf16x8_t H, L;
    split8(v0, v1, H, L);
    *(bf16x8_t*)(hiP + off) = H;
    *(bf16x8_t*)(loP + off) = L;
}

// ---------------- pass 0: init ws + pre-split W into swizzled LDS tile images ----------------
__global__ __launch_bounds__(256) void prep_kernel(
    const float* __restrict__ Wg, const float* __restrict__ Wn,
    char* __restrict__ wsW, float* __restrict__ ws)
{
    if (blockIdx.x == 128) {             // merged init
        if (threadIdx.x < WS_LIST) ws[threadIdx.x] = 0.0f;
        return;
    }
    int g = blockIdx.x * 256 + threadIdx.x;   // 0..32767
    int t = g >> 10, i = g & 1023;
    int row = i >> 3, wslot = i & 7;
    int kslot = wslot ^ (row & 7);
    const float* src = (row < 64 ? Wg + (size_t)row * IDIM
                                 : Wn + (size_t)(row - 64) * IDIM) + t * BK + kslot * 8;
    float4 v0 = *(const float4*)src;
    float4 v1 = *(const float4*)(src + 4);
    bf16x8_t H, L;
    split8(v0, v1, H, L);
    char* dst = wsW + (size_t)t * 32768;
    *(bf16x8_t*)(dst + i * 16)         = H;
    *(bf16x8_t*)(dst + 16384 + i * 16) = L;
}

// ---------------- pass 1a (split): quarter-K GEMM -> fp32 partials ----------------
// LDS exactly 40960B -> 4 blocks/CU: AH@0 AL@4096 BH@8192 BL@24576
__global__ __launch_bounds__(512, 4) void gemm_quarter_kernel(
    const float* __restrict__ x, const char* __restrict__ wsW,
    float* __restrict__ part)
{
    __shared__ char smem[40960] __attribute__((aligned(16)));
    char* AH = smem;
    char* AL = smem + 4096;
    char* BH = smem + 8192;
    char* BL = smem + 24576;

    const int u   = threadIdx.x;
    const int w   = u >> 6;
    const int l   = u & 63;
    const int lr  = l & 15;
    const int lg4 = l >> 4;
    const int s7  = lr & 7;
    const int q   = blockIdx.x & 3;
    const int row0 = (blockIdx.x >> 2) * BM;
    float* pb = part + (size_t)q * NB * 128;

    const int ar  = (u >> 3) & 31;
    const int ac  = u & 7;
    const int aoff = ar * 128 + (((ac ^ (ar & 7)) & 7) << 4);
    const float* pa = x + (size_t)(row0 + ar) * IDIM + q * KQ + ac * 8;

    f32x4_t acc[2];
    #pragma unroll
    for (int mt = 0; mt < 2; ++mt) {
        f32x4_t z = {0.f, 0.f, 0.f, 0.f};
        acc[mt] = z;
    }

    float4 ra0, ra1;
    int4 w0, w1, w2, w3;

#define QLOADT(tt) { const int k0 = (tt) * BK;                                  \
    if (u < 256) { ra0 = *(const float4*)(pa + k0);                             \
                   ra1 = *(const float4*)(pa + k0 + 4); }                       \
    const char* s_ = wsW + (size_t)(q * NCHQ + (tt)) * 32768 + u * 16;          \
    w0 = *(const int4*)(s_);          w1 = *(const int4*)(s_ + 8192);           \
    w2 = *(const int4*)(s_ + 16384);  w3 = *(const int4*)(s_ + 24576); }

    QLOADT(0);

    for (int t = 0; t < NCHQ; ++t) {
        __syncthreads();
        if (u < 256) cvt_slot(ra0, ra1, AH, AL, aoff);
        *(int4*)(BH + u * 16)        = w0;
        *(int4*)(BH + 8192 + u * 16) = w1;
        *(int4*)(BL + u * 16)        = w2;
        *(int4*)(BL + 8192 + u * 16) = w3;
        if (t + 1 < NCHQ) QLOADT(t + 1);
        __syncthreads();

        #pragma unroll
        for (int ks = 0; ks < 2; ++ks) {
            const int so = (((ks * 4 + lg4) ^ s7) << 4);
            bf16x8_t ah[2], al_[2], bh, bl;
            #pragma unroll
            for (int mt = 0; mt < 2; ++mt) {
                const int o = (mt * 16 + lr) * 128 + so;
                ah[mt]  = *(const bf16x8_t*)(AH + o);
                al_[mt] = *(const bf16x8_t*)(AL + o);
            }
            {
                const int o = (w * 16 + lr) * 128 + so;
                bh = *(const bf16x8_t*)(BH + o);
                bl = *(const bf16x8_t*)(BL + o);
            }
            #pragma unroll
            for (int mt = 0; mt < 2; ++mt) {
                acc[mt] = __builtin_amdgcn_mfma_f32_16x16x32_bf16(ah[mt],  bh, acc[mt], 0, 0, 0);
                acc[mt] = __builtin_amdgcn_mfma_f32_16x16x32_bf16(ah[mt],  bl, acc[mt], 0, 0, 0);
                acc[mt] = __builtin_amdgcn_mfma_f32_16x16x32_bf16(al_[mt], bh, acc[mt], 0, 0, 0);
            }
        }
    }

    // ---- store partials (C/D: col=lane&15, row=(lane>>4)*4+reg) ----
    #pragma unroll
    for (int mt = 0; mt < 2; ++mt)
        #pragma unroll
        for (int r = 0; r < 4; ++r)
            pb[(size_t)(row0 + mt * 16 + lg4 * 4 + r) * 128 + (w * 16 + lr)] = acc[mt][r];
}

// ---------------- pass 1b (split): gating from partials (R16 epilogue geometry) ----------------
__global__ __launch_bounds__(512) void gating_kernel(
    const float* __restrict__ part,
    const float* __restrict__ noise, const float* __restrict__ bg,
    float* __restrict__ out_w, float* __restrict__ out_i,
    float* __restrict__ ws, int listCap)
{
    __shared__ float sP[NE];
    __shared__ float sF[NE];
    __shared__ float sZ[1];
    const int u = threadIdx.x;
    const int w = u >> 6, l = u & 63;
    const int row0 = blockIdx.x * 32;
    const float* p0 = part;
    const float* p1 = part + (size_t)NB * 128;
    const float* p2 = part + 2 * (size_t)NB * 128;
    const float* p3 = part + 3 * (size_t)NB * 128;

    if (u < NE) { sP[u] = 0.f; sF[u] = 0.f; }
    if (u == 0) sZ[0] = 0.f;
    __syncthreads();

    float pacc = 0.f, zacc = 0.f;
    #pragma unroll 1
    for (int rr = 0; rr < 4; ++rr) {
        const int grow = row0 + w * 4 + rr;
        const size_t b = (size_t)grow * 128;
        float lg   = ((p0[b + l] + p1[b + l]) + (p2[b + l] + p3[b + l])) + bg[l];
        float npre = (p0[b + 64 + l] + p1[b + 64 + l]) + (p2[b + 64 + l] + p3[b + 64 + l]);
        float vcur = fmaf(noise[(size_t)grow * NE + l], softplusf(npre), lg);

        float tkv[9]; int tki[9];
        #pragma unroll
        for (int k = 0; k < 9; ++k) {
            float mv = vcur; int mi = l;
            #pragma unroll
            for (int o = 32; o > 0; o >>= 1) {
                float ov = __shfl_xor(mv, o);
                int   oi = __shfl_xor(mi, o);
                if (ov > mv || (ov == mv && oi < mi)) { mv = ov; mi = oi; }
            }
            tkv[k] = mv; tki[k] = mi;
            if (l == mi) vcur = -1e30f;
        }

        float m0 = tkv[0], s = 0.f, wk[TOPK];
        #pragma unroll
        for (int k = 0; k < TOPK; ++k) { wk[k] = expf(tkv[k] - m0); s += wk[k]; }
        float inv = 1.f / s;
        float myw = 0.f; int myi = 0;
        #pragma unroll
        for (int k = 0; k < TOPK; ++k)
            if (l == k) { myw = wk[k] * inv; myi = tki[k]; }
        if (l < TOPK) {
            out_w[(size_t)grow * TOPK + l] = myw;
            out_i[(size_t)grow * TOPK + l] = (float)myi;
        }

        if (l == 0) {
            atomicAdd(&sF[tki[0]], 1.f);
            float ming = 1e30f;
            #pragma unroll
            for (int k = 0; k < 8; ++k) ming = fminf(ming, tkv[k] - tkv[k + 1]);
            if (ming < TAU) {
                int slot = atomicAdd((int*)&ws[WS_CNT], 1);
                if (slot < listCap) ((int*)ws)[WS_LIST + slot] = grow;
            }
        }

        float rm = lg;
        #pragma unroll
        for (int o = 32; o > 0; o >>= 1) rm = fmaxf(rm, __shfl_xor(rm, o));
        float pe = expf(lg - rm);
        float ssum = pe;
        #pragma unroll
        for (int o = 32; o > 0; o >>= 1) ssum += __shfl_xor(ssum, o);
        pacc += pe / ssum;
        if (l == 0) { float lse = rm + logf(ssum); zacc += lse * lse; }
    }

    atomicAdd(&sP[l], pacc);
    if (l == 0) atomicAdd(sZ, zacc);
    __syncthreads();
    if (u < NE) {
        atomicAdd(&ws[u],      sF[u]);
        atomicAdd(&ws[NE + u], sP[u]);
    }
    if (u == 0) atomicAdd(&ws[2 * NE], sZ[0]);
}

// ---------------- pass 1 (fallback): R16 monolithic GEMM + gating ----------------
template<bool PRE>
__global__ __launch_bounds__(512, 4) void gate_main_kernel(
    const float* __restrict__ x, const float* __restrict__ noise,
    const float* __restrict__ Wg, const float* __restrict__ bg,
    const float* __restrict__ Wn, const char* __restrict__ wsW,
    float* __restrict__ out_w, float* __restrict__ out_i,
    float* __restrict__ ws, int listCap)
{
    __shared__ char smem[41488] __attribute__((aligned(16)));
    char* AH = smem;
    char* AL = smem + 4096;
    char* BH = smem + 8192;
    char* BL = smem + 24576;
    float* sP = (float*)(smem + 40960);
    float* sF = (float*)(smem + 41216);
    float* sZ = (float*)(smem + 41472);
    float* sL = (float*)smem;

    const int u   = threadIdx.x;
    const int w   = u >> 6;
    const int l   = u & 63;
    const int lr  = l & 15;
    const int lg4 = l >> 4;
    const int s7  = lr & 7;
    const int row0 = blockIdx.x * BM;

    if (u < NE) { sP[u] = 0.f; sF[u] = 0.f; }
    if (u == 0) sZ[0] = 0.f;

    const int ar  = (u >> 3) & 31;
    const int ac  = u & 7;
    const int aoff = ar * 128 + (((ac ^ (ar & 7)) & 7) << 4);
    const float* pa = x + (size_t)(row0 + ar) * IDIM + ac * 8;

    const int br  = u >> 3;
    const float* pg = Wg + (size_t)br * IDIM + ac * 8;
    const float* pn = Wn + (size_t)br * IDIM + ac * 8;
    const int woff = br * 128 + ((ac ^ (br & 7)) << 4);

    f32x4_t acc[2];
    #pragma unroll
    for (int mt = 0; mt < 2; ++mt) {
        f32x4_t z = {0.f, 0.f, 0.f, 0.f};
        acc[mt] = z;
    }

    float4 ra0, ra1;
    int4 w0, w1, w2, w3;
    float4 g0, g1, n0, n1;

#define LOADT(tt) { const int k0 = (tt) * BK;                                   \
    if (u < 256) { ra0 = *(const float4*)(pa + k0);                             \
                   ra1 = *(const float4*)(pa + k0 + 4); }                       \
    if constexpr (PRE) {                                                        \
        const char* s_ = wsW + (size_t)(tt) * 32768 + u * 16;                   \
        w0 = *(const int4*)(s_);          w1 = *(const int4*)(s_ + 8192);       \
        w2 = *(const int4*)(s_ + 16384);  w3 = *(const int4*)(s_ + 24576);      \
    } else {                                                                    \
        g0 = *(const float4*)(pg + k0);   g1 = *(const float4*)(pg + k0 + 4);   \
        n0 = *(const float4*)(pn + k0);   n1 = *(const float4*)(pn + k0 + 4);   \
    } }

    LOADT(0);

    for (int t = 0; t < NCH; ++t) {
        __syncthreads();
        if (u < 256) cvt_slot(ra0, ra1, AH, AL, aoff);
        if constexpr (PRE) {
            *(int4*)(BH + u * 16)        = w0;
            *(int4*)(BH + 8192 + u * 16) = w1;
            *(int4*)(BL + u * 16)        = w2;
            *(int4*)(BL + 8192 + u * 16) = w3;
        } else {
            cvt_slot(g0, g1, BH, BL, woff);
            cvt_slot(n0, n1, BH, BL, woff + 8192);
        }
        if (t + 1 < NCH) LOADT(t + 1);
        __syncthreads();

        #pragma unroll
        for (int ks = 0; ks < 2; ++ks) {
            const int so = (((ks * 4 + lg4) ^ s7) << 4);
            bf16x8_t ah[2], al_[2], bh, bl;
            #pragma unroll
            for (int mt = 0; mt < 2; ++mt) {
                const int o = (mt * 16 + lr) * 128 + so;
                ah[mt]  = *(const bf16x8_t*)(AH + o);
                al_[mt] = *(const bf16x8_t*)(AL + o);
            }
            {
                const int o = (w * 16 + lr) * 128 + so;
                bh = *(const bf16x8_t*)(BH + o);
                bl = *(const bf16x8_t*)(BL + o);
            }
            #pragma unroll
            for (int mt = 0; mt < 2; ++mt) {
                acc[mt] = __builtin_amdgcn_mfma_f32_16x16x32_bf16(ah[mt],  bh, acc[mt], 0, 0, 0);
                acc[mt] = __builtin_amdgcn_mfma_f32_16x16x32_bf16(ah[mt],  bl, acc[mt], 0, 0, 0);
                acc[mt] = __builtin_amdgcn_mfma_f32_16x16x32_bf16(al_[mt], bh, acc[mt], 0, 0, 0);
            }
        }
    }
    __syncthreads();

    #pragma unroll
    for (int mt = 0; mt < 2; ++mt)
        #pragma unroll
        for (int r = 0; r < 4; ++r)
            sL[(mt * 16 + lg4 * 4 + r) * 132 + (w * 16 + lr)] = acc[mt][r];
    __syncthreads();

    float pacc = 0.f, zacc = 0.f;
    #pragma unroll 1
    for (int rr = 0; rr < 4; ++rr) {
        const int r = w * 4 + rr;
        const int grow = row0 + r;
        float lg   = sL[r * 132 + l] + bg[l];
        float npre = sL[r * 132 + 64 + l];
        float vcur = fmaf(noise[(size_t)grow * NE + l], softplusf(npre), lg);

        float tkv[9]; int tki[9];
        #pragma unroll
        for (int k = 0; k < 9; ++k) {
            float mv = vcur; int mi = l;
            #pragma unroll
            for (int o = 32; o > 0; o >>= 1) {
                float ov = __shfl_xor(mv, o);
                int   oi = __shfl_xor(mi, o);
                if (ov > mv || (ov == mv && oi < mi)) { mv = ov; mi = oi; }
            }
            tkv[k] = mv; tki[k] = mi;
            if (l == mi) vcur = -1e30f;
        }

        float m0 = tkv[0], s = 0.f, wk[TOPK];
        #pragma unroll
        for (int k = 0; k < TOPK; ++k) { wk[k] = expf(tkv[k] - m0); s += wk[k]; }
        float inv = 1.f / s;
        float myw = 0.f; int myi = 0;
        #pragma unroll
        for (int k = 0; k < TOPK; ++k)
            if (l == k) { myw = wk[k] * inv; myi = tki[k]; }
        if (l < TOPK) {
            out_w[(size_t)grow * TOPK + l] = myw;
            out_i[(size_t)grow * TOPK + l] = (float)myi;
        }

        if (l == 0) {
            atomicAdd(&sF[tki[0]], 1.f);
            float ming = 1e30f;
            #pragma unroll
            for (int k = 0; k < 8; ++k) ming = fminf(ming, tkv[k] - tkv[k + 1]);
            if (ming < TAU) {
                int slot = atomicAdd((int*)&ws[WS_CNT], 1);
                if (slot < listCap) ((int*)ws)[WS_LIST + slot] = grow;
            }
        }

        float rm = lg;
        #pragma unroll
        for (int o = 32; o > 0; o >>= 1) rm = fmaxf(rm, __shfl_xor(rm, o));
        float pe = expf(lg - rm);
        float ssum = pe;
        #pragma unroll
        for (int o = 32; o > 0; o >>= 1) ssum += __shfl_xor(ssum, o);
        pacc += pe / ssum;
        if (l == 0) { float lse = rm + logf(ssum); zacc += lse * lse; }
    }

    atomicAdd(&sP[l], pacc);
    if (l == 0) atomicAdd(sZ, zacc);
    __syncthreads();
    if (u < NE) {
        atomicAdd(&ws[u],      sF[u]);
        atomicAdd(&ws[NE + u], sP[u]);
    }
    if (u == 0) atomicAdd(&ws[2 * NE], sZ[0]);
}

// ---------------- pass 2: finalize scalars (block 0) + fp64 recheck, COALESCED ----------------
// 1 row/block, 1024 threads = 16 waves x 8 slots; lane covers k (coalesced 1KB/instr).
__global__ __launch_bounds__(1024) void recheck_finalize_kernel(
    const float* __restrict__ x, const float* __restrict__ noise,
    const float* __restrict__ Wg, const float* __restrict__ bg,
    const float* __restrict__ Wn,
    float* __restrict__ out_w, float* __restrict__ out_i, float* __restrict__ out_s,
    const float* __restrict__ ws, int listCap)
{
    __shared__ double sRed[128];
    const int t = threadIdx.x;

    if (blockIdx.x == 0 && t < 64) {     // finalize scalars (wave 0, no barriers)
        float v = (ws[t] / (float)NB) * (ws[NE + t] / (float)NB);
        #pragma unroll
        for (int o = 32; o > 0; o >>= 1) v += __shfl_down(v, o);
        if (t == 0) {
            out_s[0] = (float)NE * v;
            out_s[1] = ws[2 * NE] / (float)NB;
        }
    }

    const int* wsi = (const int*)ws;
    int cnt = wsi[WS_CNT];
    if (cnt > listCap) cnt = listCap;
    if (cnt <= 0) return;

    const int wv   = t >> 6;             // wave 0..15, owns slots [wv*8, wv*8+8)
    const int lane = t & 63;

    for (int bi = blockIdx.x; bi < cnt; bi += gridDim.x) {
        const int row = wsi[WS_LIST + bi];
        const float* xr = x + (size_t)row * IDIM;

        float4 xv[8];
        #pragma unroll
        for (int i = 0; i < 8; ++i)
            xv[i] = *(const float4*)(xr + i * 256 + lane * 4);

        #pragma unroll 1
        for (int si = 0; si < 8; ++si) {
            const int s = wv * 8 + si;
            const float* wr = (s < 64) ? (Wg + (size_t)s * IDIM)
                                       : (Wn + (size_t)(s - 64) * IDIM);
            double a = 0.0;
            #pragma unroll
            for (int i = 0; i < 8; ++i) {
                float4 wvv = *(const float4*)(wr + i * 256 + lane * 4);
                a = fma((double)xv[i].x, (double)wvv.x, a);
                a = fma((double)xv[i].y, (double)wvv.y, a);
                a = fma((double)xv[i].z, (double)wvv.z, a);
                a = fma((double)xv[i].w, (double)wvv.w, a);
            }
            #pragma unroll
            for (int o = 32; o > 0; o >>= 1)
                a += __shfl_xor(a, o);
            if (lane == 0) sRed[s] = a;
        }
        __syncthreads();

        if (t < 64) {
            const int l64 = t;
            double g = sRed[l64];
            double n = sRed[64 + l64];
            double lgd = g + (double)bg[l64];
            double nz = (double)noise[(size_t)row * NE + l64];
            double vcur = fma(nz, softplus_d(n), lgd);

            double tkv[TOPK]; int tki[TOPK];
            #pragma unroll
            for (int k = 0; k < TOPK; ++k) {
                double mv = vcur; int mi = l64;
                #pragma unroll
                for (int o = 32; o > 0; o >>= 1) {
                    double ov = __shfl_xor(mv, o);
                    int    oi = __shfl_xor(mi, o);
                    if (ov > mv || (ov == mv && oi < mi)) { mv = ov; mi = oi; }
                }
                tkv[k] = mv; tki[k] = mi;
                if (l64 == mi) vcur = -1e300;
            }
            double m0 = tkv[0], s = 0.0, wk[TOPK];
            #pragma unroll
            for (int k = 0; k < TOPK; ++k) { wk[k] = exp(tkv[k] - m0); s += wk[k]; }
            double inv = 1.0 / s;
            float myw = 0.f; int myi = 0;
            #pragma unroll
            for (int k = 0; k < TOPK; ++k)
                if (l64 == k) { myw = (float)(wk[k] * inv); myi = tki[k]; }
            if (l64 < TOPK) {
                out_w[(size_t)row * TOPK + l64] = myw;
                out_i[(size_t)row * TOPK + l64] = (float)myi;
            }
        }
        __syncthreads();
    }
}

extern "C" void kernel_launch(void* const* d_in, const int* in_sizes, int n_in,
                              void* d_out, int out_size, void* d_ws, size_t ws_size,
                              hipStream_t stream) {
    const float* x     = (const float*)d_in[0];
    const float* noise = (const float*)d_in[1];
    const float* Wg    = (const float*)d_in[2];
    const float* bg    = (const float*)d_in[3];
    const float* Wn    = (const float*)d_in[4];
    float* out = (float*)d_out;
    float* ws  = (float*)d_ws;
    char*  wsW = (char*)d_ws + WSPLIT_BYTE;

    long cap = (long)(ws_size / 4) - WS_LIST;
    int listCap = (int)(cap < 0 ? 0 : (cap > NB ? NB : cap));
    const bool pre   = ws_size >= (size_t)WSPLIT_REQ;
    const bool split = ws_size >= (size_t)SPLIT_REQ;

    if (split) {
        float* part = (float*)((char*)d_ws + PART_BYTE);
        hipLaunchKernelGGL(prep_kernel, dim3(129), dim3(256), 0, stream, Wg, Wn, wsW, ws);
        hipLaunchKernelGGL(gemm_quarter_kernel, dim3(NQ * NB / BM), dim3(512), 0, stream,
                           x, wsW, part);
        hipLaunchKernelGGL(gating_kernel, dim3(NB / 32), dim3(512), 0, stream,
                           part, noise, bg,
                           out, out + (size_t)NB * TOPK, ws, listCap);
    } else if (pre) {
        hipLaunchKernelGGL(prep_kernel, dim3(129), dim3(256), 0, stream, Wg, Wn, wsW, ws);
        hipLaunchKernelGGL(gate_main_kernel<true>, dim3(NB / BM), dim3(512), 0, stream,
                           x, noise, Wg, bg, Wn, wsW,
                           out, out + (size_t)NB * TOPK, ws, listCap);
    } else {
        hipLaunchKernelGGL(init_ws_kernel, dim3(1), dim3(256), 0, stream, ws);
        hipLaunchKernelGGL(gate_main_kernel<false>, dim3(NB / BM), dim3(512), 0, stream,
                           x, noise, Wg, bg, Wn, wsW,
                           out, out + (size_t)NB * TOPK, ws, listCap);
    }
    hipLaunchKernelGGL(recheck_finalize_kernel, dim3(512), dim3(1024), 0, stream,
                       x, noise, Wg, bg, Wn,
                       out, out + (size_t)NB * TOPK, out + 2 * (size_t)NB * TOPK,
                       ws, listCap);
}